// Round 5
// baseline (48.998 us; speedup 1.0000x reference)
//
#include <hip/hip_runtime.h>
#include <hip/hip_bf16.h>

typedef __attribute__((ext_vector_type(4))) float f32x4;
typedef __attribute__((ext_vector_type(8))) __bf16 bf16x8;

#define B_DIM 16
#define L_DIM 1024
#define D_DIM 256

// ---------------------------------------------------------------------------
// Fused kernel: per 128x128 tile, stage fp32 -> regs -> (cvt bf16 + exact fp32
// norm accumulation) -> swizzled LDS; 16x16x32 bf16 MFMA; epilogue
// out = 1/(1+sqrt(max(x2+y2-2xy,0))) with norms from LDS.
//
// Pipeline per K-step kt (BK=32, 8 chunks), 2 LDS buffers:
//   readFrags(kt)            ds_read from buf[kt&1]   (published barrier@kt-1)
//   cvtWrite(kt+1)           ds_write to buf[(kt+1)&1]
//   gload(kt+2)              global->regs, stays in flight across barrier
//   lgkm(0); sched_barrier; s_barrier     (publish chunk kt+1)
//   MFMA@kt
// Overwrite safety: buf[(kt+1)&1] held chunk kt-1; its readers drained by
// each wave's lgkm(0)@kt-1 BEFORE barrier@kt-1, and cvtWrite@kt is after
// barrier@kt-1 in all waves -> no race. vmcnt never force-drained in loop
// (compiler inserts precise waits for reg consumers).
// ---------------------------------------------------------------------------
__global__ __launch_bounds__(256, 3) void dist_fused_kernel(const float* __restrict__ s1,
                                                            const float* __restrict__ s2,
                                                            float* __restrict__ out) {
    __shared__ __bf16 Alds[2][128 * 32];
    __shared__ __bf16 Blds[2][128 * 32];
    __shared__ float x2lds[128];
    __shared__ float y2lds[128];

    const int t = threadIdx.x;
    const int p = blockIdx.x;
    // XCD-aware swizzle: XCD x owns 128 consecutive logical tiles = 2 batches.
    const int d = ((p & 7) << 7) + (p >> 3);  // bijective for 1024 blocks
    const int batch = d >> 6;
    const int tile = d & 63;
    const int row0 = (tile >> 3) << 7;
    const int col0 = (tile & 7) << 7;

    const float* Ag = s1 + ((size_t)batch * L_DIM + row0) * D_DIM;
    const float* Bg = s2 + ((size_t)batch * L_DIM + col0) * D_DIM;

    const int l = t & 63, w = t >> 6;
    const int wr = w >> 1, wc = w & 1;   // wave -> 64x64 output quadrant
    const int lr = l & 15;               // frag row (A) / col (B,C)
    const int lq = l >> 4;               // quarter -> base 16B slot

    // staging: wave w owns segments {2w, 2w+1}; seg s = tile rows 16s..16s+15
    // of BOTH the A-tile and B-tile. lane l: row-in-seg = l>>2, k-slot = l&3
    // (8 floats). Swizzled 16B LDS slot: sl = kslot ^ ((row>>1)&3); since
    // row = 16s + srow, (row>>1)&3 == (srow>>1)&3 == (l>>3)&3.
    const int srow = l >> 2;
    const int kslot = l & 3;
    const int sl = kslot ^ ((l >> 3) & 3);
    const int rowA0 = ((w << 1) << 4) + srow;        // seg 2w
    const int rowA1 = (((w << 1) | 1) << 4) + srow;  // seg 2w+1

    f32x4 acc[4][4] = {};
    float xs0 = 0.f, xs1 = 0.f, ys0 = 0.f, ys1 = 0.f;

    float4 rA0a, rA0b, rA1a, rA1b, rB0a, rB0b, rB1a, rB1b;  // staging regs

    auto gload = [&](int kt) {
        const int k0 = kt << 5;
        const float* pa0 = Ag + (size_t)rowA0 * D_DIM + k0 + kslot * 8;
        const float* pa1 = Ag + (size_t)rowA1 * D_DIM + k0 + kslot * 8;
        const float* pb0 = Bg + (size_t)rowA0 * D_DIM + k0 + kslot * 8;
        const float* pb1 = Bg + (size_t)rowA1 * D_DIM + k0 + kslot * 8;
        rA0a = reinterpret_cast<const float4*>(pa0)[0];
        rA0b = reinterpret_cast<const float4*>(pa0)[1];
        rA1a = reinterpret_cast<const float4*>(pa1)[0];
        rA1b = reinterpret_cast<const float4*>(pa1)[1];
        rB0a = reinterpret_cast<const float4*>(pb0)[0];
        rB0b = reinterpret_cast<const float4*>(pb0)[1];
        rB1a = reinterpret_cast<const float4*>(pb1)[0];
        rB1b = reinterpret_cast<const float4*>(pb1)[1];
    };

    auto pack = [](const float4& u, const float4& v) {
        bf16x8 o;
        o[0] = (__bf16)u.x; o[1] = (__bf16)u.y; o[2] = (__bf16)u.z; o[3] = (__bf16)u.w;
        o[4] = (__bf16)v.x; o[5] = (__bf16)v.y; o[6] = (__bf16)v.z; o[7] = (__bf16)v.w;
        return o;
    };
    auto ssq = [](const float4& u, const float4& v) {
        return u.x * u.x + u.y * u.y + u.z * u.z + u.w * u.w +
               v.x * v.x + v.y * v.y + v.z * v.z + v.w * v.w;
    };

    auto cvtWrite = [&](int kt) {
        const int b = kt & 1;
        xs0 += ssq(rA0a, rA0b);
        xs1 += ssq(rA1a, rA1b);
        ys0 += ssq(rB0a, rB0b);
        ys1 += ssq(rB1a, rB1b);
        *reinterpret_cast<bf16x8*>(&Alds[b][(rowA0 << 5) + (sl << 3)]) = pack(rA0a, rA0b);
        *reinterpret_cast<bf16x8*>(&Alds[b][(rowA1 << 5) + (sl << 3)]) = pack(rA1a, rA1b);
        *reinterpret_cast<bf16x8*>(&Blds[b][(rowA0 << 5) + (sl << 3)]) = pack(rB0a, rB0b);
        *reinterpret_cast<bf16x8*>(&Blds[b][(rowA1 << 5) + (sl << 3)]) = pack(rB1a, rB1b);
    };

    bf16x8 aF[4], bF[4];
    auto readFrags = [&](int kt) {   // 8 ds_read_b128 from buf[kt&1]
        const int b = kt & 1;
#pragma unroll
        for (int m = 0; m < 4; ++m) {
            const int row = (wr << 6) + (m << 4) + lr;
            const int s2_ = lq ^ ((row >> 1) & 3);
            aF[m] = *reinterpret_cast<const bf16x8*>(&Alds[b][(row << 5) + (s2_ << 3)]);
        }
#pragma unroll
        for (int n = 0; n < 4; ++n) {
            const int row = (wc << 6) + (n << 4) + lr;
            const int s2_ = lq ^ ((row >> 1) & 3);
            bF[n] = *reinterpret_cast<const bf16x8*>(&Blds[b][(row << 5) + (s2_ << 3)]);
        }
    };

    // Prologue: chunk 0 staged + published; chunk 1 loads in flight.
    gload(0);
    cvtWrite(0);               // compiler inserts vmcnt wait for reg deps
    gload(1);
    asm volatile("s_waitcnt lgkmcnt(0)" ::: "memory");
    __builtin_amdgcn_sched_barrier(0);
    __builtin_amdgcn_s_barrier();

#pragma unroll
    for (int kt = 0; kt < 8; ++kt) {
        readFrags(kt);
        if (kt <= 6) {
            cvtWrite(kt + 1);
            if (kt <= 5) gload(kt + 2);
            asm volatile("s_waitcnt lgkmcnt(0)" ::: "memory");
            __builtin_amdgcn_sched_barrier(0);
            __builtin_amdgcn_s_barrier();
        }
        __builtin_amdgcn_s_setprio(1);
#pragma unroll
        for (int m = 0; m < 4; ++m)
#pragma unroll
            for (int n = 0; n < 4; ++n)
                acc[m][n] = __builtin_amdgcn_mfma_f32_16x16x32_bf16(aF[m], bF[n], acc[m][n], 0, 0, 0);
        __builtin_amdgcn_s_setprio(0);
    }

    // Exchange exact fp32 norms through LDS (reduce over the 4-lane k-slot group).
    xs0 += __shfl_xor(xs0, 1, 64); xs0 += __shfl_xor(xs0, 2, 64);
    xs1 += __shfl_xor(xs1, 1, 64); xs1 += __shfl_xor(xs1, 2, 64);
    ys0 += __shfl_xor(ys0, 1, 64); ys0 += __shfl_xor(ys0, 2, 64);
    ys1 += __shfl_xor(ys1, 1, 64); ys1 += __shfl_xor(ys1, 2, 64);
    if (kslot == 0) {
        x2lds[rowA0] = xs0; x2lds[rowA1] = xs1;
        y2lds[rowA0] = ys0; y2lds[rowA1] = ys1;
    }
    __syncthreads();

    // Epilogue
    float* outb = out + (size_t)batch * L_DIM * L_DIM;
    const int rbase = (wr << 6) + (lq << 2);
    const int cbase = (wc << 6) + lr;
#pragma unroll
    for (int n = 0; n < 4; ++n) {
        const int colt = cbase + (n << 4);
        const float y2v = y2lds[colt];
#pragma unroll
        for (int m = 0; m < 4; ++m) {
#pragma unroll
            for (int r = 0; r < 4; ++r) {
                const int rowt = rbase + (m << 4) + r;
                float sq = x2lds[rowt] + y2v - 2.0f * acc[m][n][r];
                sq = fmaxf(sq, 0.0f);
                float den = 1.0f + __builtin_amdgcn_sqrtf(sq);
                outb[(size_t)(row0 + rowt) * L_DIM + (col0 + colt)] = __builtin_amdgcn_rcpf(den);
            }
        }
    }
}

extern "C" void kernel_launch(void* const* d_in, const int* in_sizes, int n_in,
                              void* d_out, int out_size, void* d_ws, size_t ws_size,
                              hipStream_t stream) {
    (void)in_sizes; (void)n_in; (void)out_size; (void)d_ws; (void)ws_size;
    const float* s1 = (const float*)d_in[1];
    const float* s2 = (const float*)d_in[2];
    float* out = (float*)d_out;
    dist_fused_kernel<<<1024, 256, 0, stream>>>(s1, s2, out);
}

// Round 7
// 36.312 us; speedup vs baseline: 1.3494x; 1.3494x over previous
//
#include <hip/hip_runtime.h>
#include <hip/hip_bf16.h>

typedef __attribute__((ext_vector_type(4))) float f32x4;
typedef __attribute__((ext_vector_type(8))) __bf16 bf16x8;
typedef __attribute__((ext_vector_type(4))) __bf16 bf16x4;

#define B_DIM 16
#define L_DIM 1024
#define D_DIM 256

#define GLOAD_LDS16(g, lptr)                                          \
    __builtin_amdgcn_global_load_lds(                                 \
        (const __attribute__((address_space(1))) void*)(g),           \
        (__attribute__((address_space(3))) void*)(lptr), 16, 0, 0)

// ---------------------------------------------------------------------------
// Prep: row norms + fp32->bf16 conversion, XCD-matched block mapping.
// Block b runs on XCD x=b&7 (round-robin dispatch). We map it to 16-row
// group g of batches {2x, 2x+1} so the bf16 write-backs stay resident in
// XCD x's L2 — exactly where the GEMM's XCD-swizzle will read them.
//   i = b>>3 (0..255): i<128 -> s1 group g = 128x+i ; else s2 group.
// fp32 input loads are nontemporal (single-use; don't evict bf16 lines).
// ---------------------------------------------------------------------------
__global__ __launch_bounds__(256) void prep_kernel(const float* __restrict__ s1,
                                                   const float* __restrict__ s2,
                                                   float* __restrict__ nrm,
                                                   __hip_bfloat16* __restrict__ s1b,
                                                   __hip_bfloat16* __restrict__ s2b) {
    const int w = threadIdx.x >> 6, l = threadIdx.x & 63;
    const int b = blockIdx.x;
    const int x = b & 7;
    const int i = b >> 3;
    const int second = i >> 7;                    // 0: s1 region, 1: s2 region
    const int g = (x << 7) + (i & 127);           // group within the region
    const float* srcb = second ? s2 : s1;
    __hip_bfloat16* dstb = second ? s2b : s1b;
    float* nrmb = nrm + (second << 14);

    const int base = (g << 4) + (w << 2);         // first of this wave's 4 rows
#pragma unroll
    for (int j = 0; j < 4; ++j) {
        const int r = base + j;                   // row within region (0..16383)
        const float* src = srcb + (size_t)r * D_DIM;
        __hip_bfloat16* dst = dstb + (size_t)r * D_DIM;
        f32x4 v = __builtin_nontemporal_load(reinterpret_cast<const f32x4*>(src) + l);
        float s = v[0] * v[0] + v[1] * v[1] + v[2] * v[2] + v[3] * v[3];
        bf16x4 bv;
        bv[0] = (__bf16)v[0]; bv[1] = (__bf16)v[1]; bv[2] = (__bf16)v[2]; bv[3] = (__bf16)v[3];
        *reinterpret_cast<bf16x4*>(dst + l * 4) = bv;
#pragma unroll
        for (int o = 32; o > 0; o >>= 1) s += __shfl_xor(s, o, 64);
        if (l == 0) nrmb[r] = s;
    }
}

// ---------------------------------------------------------------------------
// Main GEMM (round-4 proven schedule): 4 LDS buffers, stage(kt+3) at step kt,
// counted vmcnt(4), one barrier/step, frags read one step ahead, lgkmcnt(8).
// Inputs are XCD-local L2-resident bf16 (see prep). Output stores are
// nontemporal (never re-read; keep bf16 tiles resident).
// ---------------------------------------------------------------------------
__global__ __launch_bounds__(256) void dist_gemm_bf16_kernel(const __hip_bfloat16* __restrict__ s1b,
                                                             const __hip_bfloat16* __restrict__ s2b,
                                                             const float* __restrict__ nrm,
                                                             float* __restrict__ out) {
    __shared__ __bf16 Alds[4][128 * 32];
    __shared__ __bf16 Blds[4][128 * 32];

    const int t = threadIdx.x;
    const int p = blockIdx.x;
    // XCD-aware swizzle: XCD x owns logical tiles [128x, 128x+128) = batches 2x, 2x+1.
    const int d = ((p & 7) << 7) + (p >> 3);  // bijective for 1024 blocks
    const int batch = d >> 6;
    const int tile = d & 63;
    const int row0 = (tile >> 3) << 7;
    const int col0 = (tile & 7) << 7;

    const __hip_bfloat16* Ag = s1b + ((size_t)batch * L_DIM + row0) * D_DIM;
    const __hip_bfloat16* Bg = s2b + ((size_t)batch * L_DIM + col0) * D_DIM;

    const int l = t & 63, w = t >> 6;
    const int wr = w >> 1, wc = w & 1;   // wave -> 64x64 quadrant
    const int lr = l & 15;               // frag row (A) / col (B,C)
    const int lq = l >> 4;               // quarter = base 16B slot

    const int srow_in_seg = l >> 2;
    const int sslot = (l & 3) ^ ((l >> 3) & 3);

    f32x4 acc[4][4] = {};

    auto stageK = [&](int kt) {          // 4 gload_lds, writes buf kt&3
        const int k0 = kt << 5;
        const int b = kt & 3;
#pragma unroll
        for (int i = 0; i < 2; ++i) {
            const int s = (w << 1) | i;
            const int rl = (s << 4) + srow_in_seg;
            GLOAD_LDS16(Ag + rl * D_DIM + k0 + sslot * 8, &Alds[b][s << 9]);
            GLOAD_LDS16(Bg + rl * D_DIM + k0 + sslot * 8, &Blds[b][s << 9]);
        }
    };

    auto readFrags = [&](int kt, bf16x8* aF, bf16x8* bF) {  // 8 ds_read_b128
        const int b = kt & 3;
#pragma unroll
        for (int m = 0; m < 4; ++m) {
            const int row = (wr << 6) + (m << 4) + lr;
            const int sl = lq ^ ((row >> 1) & 3);
            aF[m] = *reinterpret_cast<const bf16x8*>(&Alds[b][(row << 5) + (sl << 3)]);
        }
#pragma unroll
        for (int n = 0; n < 4; ++n) {
            const int row = (wc << 6) + (n << 4) + lr;
            const int sl = lq ^ ((row >> 1) & 3);
            bF[n] = *reinterpret_cast<const bf16x8*>(&Blds[b][(row << 5) + (sl << 3)]);
        }
    };

    bf16x8 aF[2][4], bF[2][4];

    // Prologue: 3 stages in flight; drain stage0+stage1 (C@0 reads frags(1)).
    stageK(0); stageK(1); stageK(2);                     // 12 loads
    asm volatile("s_waitcnt vmcnt(4)" ::: "memory");     // stage0, stage1 landed
    __builtin_amdgcn_s_barrier();
    readFrags(0, aF[0], bF[0]);

#pragma unroll
    for (int kt = 0; kt < 8; ++kt) {
        if (kt >= 1) {
            if (kt <= 5) asm volatile("s_waitcnt vmcnt(4)" ::: "memory");
            else         asm volatile("s_waitcnt vmcnt(0)" ::: "memory");
            __builtin_amdgcn_s_barrier();
        }
        if (kt < 7) readFrags(kt + 1, aF[(kt + 1) & 1], bF[(kt + 1) & 1]);
        if (kt < 7) asm volatile("s_waitcnt lgkmcnt(8)" ::: "memory");
        else        asm volatile("s_waitcnt lgkmcnt(0)" ::: "memory");
        if (kt <= 4) stageK(kt + 3);

        __builtin_amdgcn_s_setprio(1);
#pragma unroll
        for (int m = 0; m < 4; ++m)
#pragma unroll
            for (int n = 0; n < 4; ++n)
                acc[m][n] = __builtin_amdgcn_mfma_f32_16x16x32_bf16(
                    aF[kt & 1][m], bF[kt & 1][n], acc[m][n], 0, 0, 0);
        __builtin_amdgcn_s_setprio(0);
    }

    // epilogue (nontemporal stores: output is never re-read)
    const float* x2 = nrm + batch * L_DIM;
    const float* y2 = nrm + B_DIM * L_DIM + batch * L_DIM;
    float* outb = out + (size_t)batch * L_DIM * L_DIM;
    const int rbase = row0 + (wr << 6) + (lq << 2);
    const int cbase = col0 + (wc << 6) + lr;
#pragma unroll
    for (int n = 0; n < 4; ++n) {
        const int col = cbase + (n << 4);
        const float y2v = y2[col];
#pragma unroll
        for (int m = 0; m < 4; ++m) {
            const int rowf = rbase + (m << 4);
#pragma unroll
            for (int r = 0; r < 4; ++r) {
                const int row = rowf + r;
                float sq = x2[row] + y2v - 2.0f * acc[m][n][r];
                sq = fmaxf(sq, 0.0f);
                float den = 1.0f + __builtin_amdgcn_sqrtf(sq);
                __builtin_nontemporal_store(__builtin_amdgcn_rcpf(den),
                                            &outb[(size_t)row * L_DIM + col]);
            }
        }
    }
}

// ---------------------------------------------------------------------------
// Fallback path for the case ws_size < needed.
// ---------------------------------------------------------------------------
__global__ __launch_bounds__(256) void norms_kernel(const float* __restrict__ s1,
                                                    const float* __restrict__ s2,
                                                    float* __restrict__ nrm) {
    int w = threadIdx.x >> 6, l = threadIdx.x & 63;
    int row = (blockIdx.x << 2) + w;
    const float* src = (row < B_DIM * L_DIM)
                           ? (s1 + (size_t)row * D_DIM)
                           : (s2 + (size_t)(row - B_DIM * L_DIM) * D_DIM);
    float4 v = reinterpret_cast<const float4*>(src)[l];
    float s = v.x * v.x + v.y * v.y + v.z * v.z + v.w * v.w;
#pragma unroll
    for (int o = 32; o > 0; o >>= 1) s += __shfl_xor(s, o, 64);
    if (l == 0) nrm[row] = s;
}

__global__ __launch_bounds__(256) void dist_gemm_kernel(const float* __restrict__ s1,
                                                        const float* __restrict__ s2,
                                                        const float* __restrict__ nrm,
                                                        float* __restrict__ out) {
    __shared__ __bf16 Alds[2][128 * 32];
    __shared__ __bf16 Blds[2][128 * 32];

    const int t = threadIdx.x;
    const int p = blockIdx.x;
    const int d = ((p & 7) << 7) + (p >> 3);
    const int batch = d >> 6;
    const int tile = d & 63;
    const int row0 = (tile >> 3) << 7;
    const int col0 = (tile & 7) << 7;

    const float* Ag = s1 + ((size_t)batch * L_DIM + row0) * D_DIM;
    const float* Bg = s2 + ((size_t)batch * L_DIM + col0) * D_DIM;

    const int sr = t >> 2;
    const int sc = (t & 3) << 3;

    const int l = t & 63, w = t >> 6;
    const int wr = w >> 1, wc = w & 1;
    const int lr = l & 15;
    const int lk = (l >> 4) << 3;

    f32x4 acc[4][4] = {};

    auto stage = [&](int buf, int k0) {
#pragma unroll
        for (int pass = 0; pass < 2; ++pass) {
            const int r = sr + (pass << 6);
            const float4* sa = reinterpret_cast<const float4*>(Ag + (size_t)r * D_DIM + k0 + sc);
            float4 a0 = sa[0], a1 = sa[1];
            const float4* sb = reinterpret_cast<const float4*>(Bg + (size_t)r * D_DIM + k0 + sc);
            float4 b0 = sb[0], b1 = sb[1];
            bf16x8 av, bv;
            av[0] = (__bf16)a0.x; av[1] = (__bf16)a0.y; av[2] = (__bf16)a0.z; av[3] = (__bf16)a0.w;
            av[4] = (__bf16)a1.x; av[5] = (__bf16)a1.y; av[6] = (__bf16)a1.z; av[7] = (__bf16)a1.w;
            bv[0] = (__bf16)b0.x; bv[1] = (__bf16)b0.y; bv[2] = (__bf16)b0.z; bv[3] = (__bf16)b0.w;
            bv[4] = (__bf16)b1.x; bv[5] = (__bf16)b1.y; bv[6] = (__bf16)b1.z; bv[7] = (__bf16)b1.w;
            *reinterpret_cast<bf16x8*>(&Alds[buf][(r << 5) + sc]) = av;
            *reinterpret_cast<bf16x8*>(&Blds[buf][(r << 5) + sc]) = bv;
        }
    };

    stage(0, 0);
    __syncthreads();
    int cur = 0;
    for (int kt = 0; kt < 8; ++kt) {
        if (kt < 7) stage(cur ^ 1, (kt + 1) << 5);
        bf16x8 aF[4], bF[4];
#pragma unroll
        for (int m = 0; m < 4; ++m)
            aF[m] = *reinterpret_cast<const bf16x8*>(
                &Alds[cur][(((wr << 6) + (m << 4) + lr) << 5) + lk]);
#pragma unroll
        for (int n = 0; n < 4; ++n)
            bF[n] = *reinterpret_cast<const bf16x8*>(
                &Blds[cur][(((wc << 6) + (n << 4) + lr) << 5) + lk]);
#pragma unroll
        for (int m = 0; m < 4; ++m)
#pragma unroll
            for (int n = 0; n < 4; ++n)
                acc[m][n] = __builtin_amdgcn_mfma_f32_16x16x32_bf16(aF[m], bF[n], acc[m][n], 0, 0, 0);
        __syncthreads();
        cur ^= 1;
    }

    const float* x2 = nrm + batch * L_DIM;
    const float* y2 = nrm + B_DIM * L_DIM + batch * L_DIM;
    float* outb = out + (size_t)batch * L_DIM * L_DIM;
    const int rbase = row0 + (wr << 6) + ((l >> 4) << 2);
    const int cbase = col0 + (wc << 6) + lr;
#pragma unroll
    for (int n = 0; n < 4; ++n) {
        const int col = cbase + (n << 4);
        const float y2v = y2[col];
#pragma unroll
        for (int m = 0; m < 4; ++m) {
            const int rowf = rbase + (m << 4);
#pragma unroll
            for (int r = 0; r < 4; ++r) {
                const int row = rowf + r;
                float sq = x2[row] + y2v - 2.0f * acc[m][n][r];
                sq = fmaxf(sq, 0.0f);
                outb[(size_t)row * L_DIM + col] = 1.0f / (1.0f + sqrtf(sq));
            }
        }
    }
}

extern "C" void kernel_launch(void* const* d_in, const int* in_sizes, int n_in,
                              void* d_out, int out_size, void* d_ws, size_t ws_size,
                              hipStream_t stream) {
    (void)in_sizes; (void)n_in; (void)out_size;
    const float* s1 = (const float*)d_in[1];
    const float* s2 = (const float*)d_in[2];
    float* out = (float*)d_out;

    const size_t NRM_BYTES = 2u * B_DIM * L_DIM * sizeof(float);          // 128 KB
    const size_t BF_BYTES = (size_t)B_DIM * L_DIM * D_DIM * sizeof(__hip_bfloat16);  // 8 MB each
    const size_t NEED = NRM_BYTES + 2 * BF_BYTES;                          // ~16.9 MB

    float* nrm = (float*)d_ws;
    if (ws_size >= NEED) {
        __hip_bfloat16* s1b = (__hip_bfloat16*)((char*)d_ws + NRM_BYTES);
        __hip_bfloat16* s2b = (__hip_bfloat16*)((char*)d_ws + NRM_BYTES + BF_BYTES);
        prep_kernel<<<2048, 256, 0, stream>>>(s1, s2, nrm, s1b, s2b);
        dist_gemm_bf16_kernel<<<1024, 256, 0, stream>>>(s1b, s2b, nrm, out);
    } else {
        norms_kernel<<<8192, 256, 0, stream>>>(s1, s2, nrm);
        dist_gemm_kernel<<<1024, 256, 0, stream>>>(s1, s2, nrm, out);
    }
}